// Round 4
// baseline (536.646 us; speedup 1.0000x reference)
//
#include <hip/hip_runtime.h>
#include <stdint.h>

#define NPIX 16384
#define IMW 128
#define NIMG 8
#define NLVL 11
#define BIGK 0xFFFFFFFFu
#define IMASK 16383u
#define DONE 0x0D0E0D0Eu   // != 0xAAAAAAAA ws-poison, so flags need no init

// ---------------- key-based union-find (u32 keys in LDS) — r12/r14-verified ----------------
__device__ __forceinline__ unsigned findk(volatile unsigned* par, unsigned i) {
    unsigned k = par[i];
    for (;;) {
        unsigned j = k & IMASK;
        unsigned pk = par[j];
        if (pk == k) return k;
        par[i] = pk;                 // path halving (benign race, ancestor only)
        i = j; k = pk;
    }
}

// union at round l; on absorbing root hi, record its death level (once per pixel:
// a root's par changes ONLY via this CAS, and values strictly decrease).
__device__ __forceinline__ void unionk_d(volatile unsigned* par, unsigned* par32,
                                         unsigned a, unsigned b, int l,
                                         uint8_t* __restrict__ db) {
    unsigned ka = findk(par, a);
    unsigned kb = findk(par, b);
    while (ka != kb) {
        unsigned hi = max(ka, kb);   // younger root key: absorbed -> dies at l
        unsigned lo = min(ka, kb);   // elder root key: survives
        unsigned hidx = hi & IMASK;
        if (atomicCAS(par32 + hidx, hi, lo) == hi) { db[hidx] = (uint8_t)l; return; }
        ka = findk(par, hidx);
        kb = findk(par, lo & IMASK);
    }
}

__device__ __forceinline__ void flag_release(unsigned* p) {
    __threadfence();
    __hip_atomic_store(p, DONE, __ATOMIC_RELEASE, __HIP_MEMORY_SCOPE_AGENT);
}
__device__ __forceinline__ void flag_acquire(unsigned* p) {
    while (__hip_atomic_load(p, __ATOMIC_ACQUIRE, __HIP_MEMORY_SCOPE_AGENT) != DONE)
        __builtin_amdgcn_s_sleep(2);
}

__device__ __forceinline__ unsigned nib4(unsigned p0, unsigned p1, int k) {
    unsigned v = (k < 8) ? (p0 >> (k * 4)) : (p1 >> ((k - 8) * 4));
    return v & 15u;
}

// ============ single dispatch, 9 blocks: 8× per-image full persistence + 1 wdist ============
// ONE union-find pass per image (Kruskal by level rounds), deaths recorded at CAS-absorb.
// Replaces 11 redundant per-level CCLs + bitplanes + flags. Levels live in 2 nibble-packed
// registers per thread; neighbor levels via shfl / par-key level field (monotone, race-safe).
// Layout: pixel i = w*1024 + k*64 + lane  ->  row = 8w + (k>>1), col = (k&1)*64 + lane.
// So: vertical neighbors are k+-2 (same thread!), horizontal are lane+-1 (shfl), with
// chunk seams at lane 0/63 odd/even k, and strip seams (w+-1) tested via par[i+-128]>>14.
__global__ __launch_bounds__(1024) void topo_fused(const float* __restrict__ model_output,
                                                   const float* __restrict__ labels,
                                                   uint8_t* __restrict__ lvlg,
                                                   uint8_t* __restrict__ dbg,
                                                   float* __restrict__ outP,
                                                   float* __restrict__ outB,
                                                   float* __restrict__ outD,
                                                   unsigned* __restrict__ dflags,
                                                   float* __restrict__ out)
{
    __shared__ __align__(16) unsigned char smem[65536];
    int blk = blockIdx.x;
    int tid = threadIdx.x;
    unsigned lane = tid & 63u;
    int w = tid >> 6;

    if (blk < 8) {
        int img = blk;
        bool ismask = img < 4;
        const float* src = ismask ? (labels + (size_t)img * NPIX)
                                  : (model_output + (size_t)(img - 4) * NPIX);
        uint8_t* lvl_i = lvlg + (size_t)img * NPIX;
        uint8_t* db_i  = dbg  + (size_t)img * NPIX;
        unsigned* s_par = (unsigned*)smem;     // 64 KB during rounds
        volatile unsigned* par = s_par;
        float*    s_redf = (float*)smem;       // scratch (pre-par-init only)
        unsigned* s_redu = (unsigned*)smem;

        // zero this image's death array (ws poisoned 0xAA); 1 uint4 per thread = 16 KB
        ((uint4*)db_i)[tid] = make_uint4(0, 0, 0, 0);

        // ---- quantize pass 1: minmax (pred only), regs only ----
        float mn = 0.f, mx = 1.f;
        if (!ismask) {   // block-uniform branch
            float lmn = 1e30f, lmx = -1e30f;
#pragma unroll
            for (int k = 0; k < 16; ++k) {
                int i = (w << 10) + (k << 6) + (int)lane;
                float s = 1.0f / (1.0f + expf(-src[i]));
                lmn = fminf(lmn, s); lmx = fmaxf(lmx, s);
            }
            for (int off = 32; off > 0; off >>= 1) {
                lmn = fminf(lmn, __shfl_down(lmn, off));
                lmx = fmaxf(lmx, __shfl_down(lmx, off));
            }
            if (lane == 0u) { s_redf[w] = lmn; s_redf[16 + w] = lmx; }
            __syncthreads();
            if (tid == 0) {
                float a = s_redf[0], c = s_redf[16];
                for (int u = 1; u < 16; ++u) { a = fminf(a, s_redf[u]); c = fmaxf(c, s_redf[16 + u]); }
                s_redf[32] = a; s_redf[33] = c;
            }
            __syncthreads();
            mn = s_redf[32]; mx = s_redf[33];
            __syncthreads();   // all reads done before scratch reuse below
        }
        float denom = mx - mn;
        if (denom <= 0.f) denom = 1.f;

        // ---- quantize pass 2 (cache-hot re-read): nibble packs + lvlg + maxL/argmin ----
        unsigned pack0 = 0, pack1 = 0, lmaxk = 0, bestk = BIGK;
#pragma unroll
        for (int k = 0; k < 16; ++k) {
            int i = (w << 10) + (k << 6) + (int)lane;
            float x = src[i];
            int L = ismask ? (int)rintf(x * 10.0f)
                           : (int)rintf((1.0f / (1.0f + expf(-x)) - mn) / denom * 10.0f);
            if (k < 8) pack0 |= (unsigned)L << (k * 4);
            else       pack1 |= (unsigned)L << ((k - 8) * 4);
            lvl_i[i] = (uint8_t)L;
            unsigned key = ((unsigned)L << 14) | (unsigned)i;
            lmaxk = max(lmaxk, (unsigned)L);
            bestk = min(bestk, key);
        }
        for (int off = 32; off > 0; off >>= 1) {
            lmaxk = max(lmaxk, (unsigned)__shfl_down((int)lmaxk, off));
            bestk = min(bestk, (unsigned)__shfl_down((int)bestk, off));
        }
        if (lane == 0u) { s_redu[w] = lmaxk; s_redu[16 + w] = bestk; }
        __syncthreads();
        if (tid == 0) {
            unsigned m = s_redu[0], bk = s_redu[16];
            for (int u = 1; u < 16; ++u) { m = max(m, s_redu[u]); bk = min(bk, s_redu[16 + u]); }
            s_redu[32] = m; s_redu[33] = bk;
        }
        __syncthreads();
        int maxL = (int)s_redu[32];
        unsigned amin = s_redu[33] & IMASK;
        __syncthreads();   // everyone has read scratch; par init may overwrite

        // ---- par init: every pixel its own root ----
#pragma unroll
        for (int k = 0; k < 16; ++k) {
            int i = (w << 10) + (k << 6) + (int)lane;
            s_par[i] = (nib4(pack0, pack1, k) << 14) | (unsigned)i;
        }
        // neighbor level packs (wave-internal, computed once)
        unsigned pL0 = (unsigned)__shfl_up((int)pack0, 1, 64);    // lane-1 (left, same k)
        unsigned pL1 = (unsigned)__shfl_up((int)pack1, 1, 64);
        unsigned pR0 = (unsigned)__shfl_down((int)pack0, 1, 64);  // lane+1 (right, same k)
        unsigned pR1 = (unsigned)__shfl_down((int)pack1, 1, 64);
        unsigned p63_0 = (unsigned)__shfl((int)pack0, 63, 64);    // lane 63 (left seam)
        unsigned p63_1 = (unsigned)__shfl((int)pack1, 63, 64);
        unsigned p00_0 = (unsigned)__shfl((int)pack0, 0, 64);     // lane 0 (right seam)
        unsigned p00_1 = (unsigned)__shfl((int)pack1, 0, 64);
        __syncthreads();

        // ---- level rounds: edge (a,b) processed at round max(lvl a, lvl b) ----
        // from pixel at its own level l: left/up if neighbor lvl <= l; right/down if < l
        // (strict, dedupes equal-level pairs). Cross-strip tests use par-key level field:
        // monotone non-increasing, so <=l / <l threshold tests are race-safe; worst case
        // duplicate unions, which are idempotent.
        for (int l = 0; l <= maxL; ++l) {
            for (int k = 0; k < 16; ++k) {
                if ((int)nib4(pack0, pack1, k) != l) continue;
                int i = (w << 10) + (k << 6) + (int)lane;
                // left (col-1)
                if (lane > 0u) {
                    if ((int)nib4(pL0, pL1, k) <= l) unionk_d(par, s_par, (unsigned)i, (unsigned)(i - 1), l, db_i);
                } else if (k & 1) {
                    if ((int)nib4(p63_0, p63_1, k - 1) <= l) unionk_d(par, s_par, (unsigned)i, (unsigned)(i - 1), l, db_i);
                }
                // right (col+1), strict
                if (lane < 63u) {
                    if ((int)nib4(pR0, pR1, k) < l) unionk_d(par, s_par, (unsigned)i, (unsigned)(i + 1), l, db_i);
                } else if (!(k & 1)) {
                    if ((int)nib4(p00_0, p00_1, k + 1) < l) unionk_d(par, s_par, (unsigned)i, (unsigned)(i + 1), l, db_i);
                }
                // up (row-1)
                if (k >= 2) {
                    if ((int)nib4(pack0, pack1, k - 2) <= l) unionk_d(par, s_par, (unsigned)i, (unsigned)(i - IMW), l, db_i);
                } else if (w >= 1) {
                    if ((int)(s_par[i - IMW] >> 14) <= l) unionk_d(par, s_par, (unsigned)i, (unsigned)(i - IMW), l, db_i);
                }
                // down (row+1), strict
                if (k <= 13) {
                    if ((int)nib4(pack0, pack1, k + 2) < l) unionk_d(par, s_par, (unsigned)i, (unsigned)(i + IMW), l, db_i);
                } else if (w <= 14) {
                    if ((int)(s_par[i + IMW] >> 14) < l) unionk_d(par, s_par, (unsigned)i, (unsigned)(i + IMW), l, db_i);
                }
            }
            __syncthreads();   // deaths of round l exact before round l+1
        }

        // ---- selection: top-256 by (pers desc, idx asc); par LDS dead -> overlay ----
        unsigned long long* s_bm = (unsigned long long*)smem;     // 2048
        unsigned* s_keys = (unsigned*)(smem + 2048);              // 1024
        unsigned* s_pc   = (unsigned*)(smem + 3072);              // 1024
        unsigned* s_hist = (unsigned*)(smem + 4096);              // 256
        uint8_t*  s_rtab = (uint8_t*)(smem + 4352);               // 128
        unsigned* s_ctl  = (unsigned*)(smem + 4480);              // 64

        if (tid < 64) s_hist[tid] = 0;
        if (tid < 256) { s_bm[tid] = 0ull; s_keys[tid] = 0xFFFFFFFFu; }
        if (tid < NLVL * NLVL) {
            int d = tid / NLVL, bb0 = tid % NLVL;
            if (d > bb0) {
                float pers = (float)d / 10.0f - (float)bb0 / 10.0f;
                unsigned rk = 0;
                for (int dd = 1; dd <= 10; ++dd)
                    for (int bb = 0; bb < dd; ++bb) {
                        float pp = (float)dd / 10.0f - (float)bb / 10.0f;
                        rk += (pp > pers) ? 1u : 0u;
                    }
                s_rtab[d * NLVL + bb0] = (uint8_t)rk;
            }
        }
        __syncthreads();

        // pass 1: histogram of ranks (b from packs, d from db / essential override)
#pragma unroll
        for (int k = 0; k < 16; ++k) {
            int i = (w << 10) + (k << 6) + (int)lane;
            int b = (int)nib4(pack0, pack1, k);
            int d = ((unsigned)i == amin) ? maxL : (int)db_i[i];
            if (d > b) atomicAdd(&s_hist[s_rtab[d * NLVL + b]], 1u);
        }
        __syncthreads();

        if (tid == 0) {
            unsigned cum = 0, rstar = 63, cless = 0;
            for (int r = 0; r < 56; ++r) {
                if (cum + s_hist[r] >= 256u && rstar == 63u) { rstar = r; cless = cum; }
                cum += s_hist[r];
            }
            if (rstar == 63u) cless = cum;
            s_ctl[0] = rstar; s_ctl[1] = cless;
            s_ctl[2] = (rstar == 63u) ? 0u : (256u - cless);
            s_ctl[3] = 0;
        }
        __syncthreads();
        unsigned rstar = s_ctl[0], cless = s_ctl[1], mneed = s_ctl[2];

        // pass 2: compact rank<r*; bitmap for rank==r*
#pragma unroll
        for (int k = 0; k < 16; ++k) {
            int i = (w << 10) + (k << 6) + (int)lane;
            int b = (int)nib4(pack0, pack1, k);
            int d = ((unsigned)i == amin) ? maxL : (int)db_i[i];
            if (d <= b) continue;
            unsigned r = s_rtab[d * NLVL + b];
            if (r < rstar) {
                unsigned pos = atomicAdd(&s_ctl[3], 1u);
                if (pos < 256u) s_keys[pos] = (r << 14) | (unsigned)i;
            } else if (r == rstar) {
                atomicOr(&s_bm[i >> 6], 1ull << (i & 63));
            }
        }
        __syncthreads();

        // rank-sort 256 keys ascending (2 barriers; sentinel ties by slot index)
        unsigned myk = 0, mypos = 0;
        if (tid < 256) {
            myk = s_keys[tid];
            unsigned cnt = 0;
            for (int j = 0; j < 256; ++j) {
                unsigned y = s_keys[j];
                cnt += (y < myk) || (y == myk && j < tid);
            }
            mypos = cnt;
        }
        __syncthreads();
        if (tid < 256) s_keys[mypos] = myk;

        // bucket r*: popcount prefix via wave shfl scan
        if (tid < 256) {
            unsigned v = (unsigned)__popcll(s_bm[tid]);
#pragma unroll
            for (int d = 1; d < 64; d <<= 1) {
                unsigned o = __shfl_up(v, d, 64);
                if ((int)lane >= d) v += o;
            }
            s_pc[tid] = v;
            if (lane == 63u) s_ctl[8 + (tid >> 6)] = v;
        }
        __syncthreads();
        if (tid < 256) {
            unsigned add = 0; int wq = tid >> 6;
            for (int u = 0; u < wq; ++u) add += s_ctl[8 + u];
            s_pc[tid] += add;
        }
        __syncthreads();
        if (rstar != 63u) {
            for (int i = tid; i < NPIX; i += 1024) {
                if (!((s_bm[i >> 6] >> (i & 63)) & 1ull)) continue;
                unsigned wq = i >> 6;
                unsigned order = (wq ? s_pc[wq - 1] : 0u)
                               + (unsigned)__popcll(s_bm[wq] & ((1ull << (i & 63)) - 1ull));
                if (order < mneed) s_keys[cless + order] = (rstar << 14) | (unsigned)i;
            }
        }
        __syncthreads();

        if (tid < 256) {
            unsigned key = s_keys[tid];
            float p = 0.f, bv = 0.f, dv = 0.f;
            if (key != 0xFFFFFFFFu) {
                unsigned i = key & IMASK;
                int b = (int)lvl_i[i];
                int d = (i == amin) ? maxL : (int)db_i[i];
                bv = (float)b / 10.0f;
                dv = (float)d / 10.0f;
                p = dv - bv;
            }
            outP[img * 256 + tid] = p;
            outB[img * 256 + tid] = bv;
            outD[img * 256 + tid] = dv;
        }
        __syncthreads();
        if (tid == 0) flag_release(&dflags[img]);
        return;
    }

    // ================= wdist (verified body) =================
    {
        if (tid < 8) flag_acquire(&dflags[tid]);
        __syncthreads();

        float* part = (float*)smem;          // [16]
        float* dist = (float*)(smem + 64);   // [4]
        int s = tid >> 8;
        int slot = tid & 255;
        int mi = s * 256 + slot;
        int pi = (4 + s) * 256 + slot;
        float p1 = outP[mi], b1 = outB[mi], d1 = outD[mi];
        float p2 = outP[pi], b2 = outB[pi], d2 = outD[pi];
        bool h1 = p1 > 0.f, h2 = p2 > 0.f;
        float cost = 0.f;
        if (h1 && h2)      cost = (b1 - b2) * (b1 - b2) + (d1 - d2) * (d1 - d2);
        else if (h1)       cost = p1 * p1 * 0.5f;
        else if (h2)       cost = p2 * p2 * 0.5f;

        for (int off = 32; off > 0; off >>= 1) cost += __shfl_down(cost, off);
        int wv = tid >> 6;
        if (lane == 0u) part[wv] = cost;
        __syncthreads();
        if (tid < 4) {
            float sum = part[tid * 4] + part[tid * 4 + 1] + part[tid * 4 + 2] + part[tid * 4 + 3];
            dist[tid] = sqrtf(sum + 1e-12f);
        }
        __syncthreads();
        if (tid == 0)
            out[0] = 0.01f * (dist[0] + dist[1] + dist[2] + dist[3]) / 4.0f;
    }
}

// ws layout (bytes):
//   lvlg u8[8][16384]           @ 0        (131072)
//   db   u8[8][16384]           @ 131072   (131072)  -- death level per pixel
//   outP/outB/outD f32[8][256]  @ 262144   (24576)
//   dflags u32[8]               @ 286720   (32)
extern "C" void kernel_launch(void* const* d_in, const int* in_sizes, int n_in,
                              void* d_out, int out_size, void* d_ws, size_t ws_size,
                              hipStream_t stream)
{
    const float* model_output = (const float*)d_in[0];
    const float* labels = (const float*)d_in[1];
    char* ws = (char*)d_ws;
    uint8_t* lvlg = (uint8_t*)ws;
    uint8_t* dbg  = (uint8_t*)(ws + 131072);
    float* outP = (float*)(ws + 262144);
    float* outB = outP + NIMG * 256;
    float* outD = outB + NIMG * 256;
    unsigned* dflags = (unsigned*)(ws + 286720);
    float* out = (float*)d_out;

    topo_fused<<<9, 1024, 0, stream>>>(model_output, labels, lvlg, dbg,
                                       outP, outB, outD, dflags, out);
}

// Round 5
// 112.979 us; speedup vs baseline: 4.7500x; 4.7500x over previous
//
#include <hip/hip_runtime.h>
#include <stdint.h>

#define NPIX 16384
#define IMW 128
#define NIMG 8
#define NLVL 11
#define BIGK 0xFFFFFFFFu
#define IMASK 16383u
#define DONE 0x0D0E0D0Eu   // != 0xAAAAAAAA ws-poison, so flags need no init

// ---------------- key-based union-find (u32 keys in LDS) — r12/r14-verified ----------------
__device__ __forceinline__ unsigned findk(volatile unsigned* par, unsigned i) {
    unsigned k = par[i];
    for (;;) {
        unsigned j = k & IMASK;
        unsigned pk = par[j];
        if (pk == k) return k;
        par[i] = pk;                 // path halving (benign race, ancestor only)
        i = j; k = pk;
    }
}

__device__ __forceinline__ void unionk(volatile unsigned* par, unsigned* par32,
                                       unsigned a, unsigned b) {
    unsigned ka = findk(par, a);
    unsigned kb = findk(par, b);
    while (ka != kb) {
        unsigned hi = max(ka, kb);
        unsigned lo = min(ka, kb);
        unsigned hidx = hi & IMASK;
        if (atomicCAS(par32 + hidx, hi, lo) == hi) return;
        ka = findk(par, hidx);
        kb = findk(par, lo & IMASK);
    }
}

__device__ __forceinline__ void flag_release(unsigned* p) {
    __threadfence();
    __hip_atomic_store(p, DONE, __ATOMIC_RELEASE, __HIP_MEMORY_SCOPE_AGENT);
}
__device__ __forceinline__ void flag_acquire(unsigned* p) {
    while (__hip_atomic_load(p, __ATOMIC_ACQUIRE, __HIP_MEMORY_SCOPE_AGENT) != DONE)
        __builtin_amdgcn_s_sleep(2);
}

__device__ __forceinline__ unsigned nib4(unsigned p0, unsigned p1, int k) {
    unsigned v = (k < 8) ? (p0 >> (k * 4)) : (p1 >> ((k - 8) * 4));
    return v & 15u;
}

// ============== single dispatch: 88 ccl + 8 death + 1 wdist = 97 blocks ==============
// Deaths via SPARSE global atomicMax: root-bits per pixel are CONTIGUOUS in level
// (component min-key monotone non-increasing), so lastroot[i] (max level where i is
// root, signed) determines death = lastroot+1, clamped to maxL (essential class falls
// out uniformly). ws poison 0xAAAAAAAA is NEGATIVE as int -> -inf for atomicMax, no init.
// CCL = r3-verified run-scan + union-find; quantize single-read via s_par float staging.
__global__ __launch_bounds__(1024) void topo_fused(const float* __restrict__ model_output,
                                                   const float* __restrict__ labels,
                                                   int* __restrict__ lastroot,
                                                   float* __restrict__ outP,
                                                   float* __restrict__ outB,
                                                   float* __restrict__ outD,
                                                   unsigned* __restrict__ flags,
                                                   unsigned* __restrict__ dflags,
                                                   float* __restrict__ out)
{
    __shared__ __align__(16) unsigned char smem[65536];
    int blk = blockIdx.x;
    int tid = threadIdx.x;
    unsigned lane = tid & 63u;
    int w = tid >> 6;                  // wave id == 8-row strip id

    if (blk < 88) {
        // ================= ccl(img, l) =================
        int img = blk / NLVL, l = blk % NLVL;
        bool ismask = img < 4;
        const float* src = ismask ? (labels + (size_t)img * NPIX)
                                  : (model_output + (size_t)(img - 4) * NPIX);
        int* lr_i = lastroot + (size_t)img * NPIX;
        unsigned* s_par = (unsigned*)smem;     // 64 KB
        volatile unsigned* par = s_par;
        float* s_sig = (float*)smem;           // aliases par: sigmoid staging, consumed
                                               // per-thread-slot before key overwrite
        float mn = 0.f, mx = 1.f;
        if (!ismask) {   // block-uniform branch: barriers inside are safe
            // pass 1: sigmoid -> s_sig + running minmax (single global read + expf)
            float lmn = 1e30f, lmx = -1e30f;
#pragma unroll
            for (int k = 0; k < 16; ++k) {
                int i = (w << 10) + (k << 6) + (int)lane;
                float s = 1.0f / (1.0f + expf(-src[i]));
                s_sig[i] = s;
                lmn = fminf(lmn, s); lmx = fmaxf(lmx, s);
            }
            for (int off = 32; off > 0; off >>= 1) {
                lmn = fminf(lmn, __shfl_down(lmn, off));
                lmx = fmaxf(lmx, __shfl_down(lmx, off));
            }
            // reduce scratch = s_sig[0..33] (wave0/k0 slots; wave0 recomputes k0 later)
            if (lane == 0u) { s_sig[w] = lmn; s_sig[16 + w] = lmx; }
            __syncthreads();
            if (tid == 0) {
                float a = s_sig[0], c = s_sig[16];
                for (int u = 1; u < 16; ++u) { a = fminf(a, s_sig[u]); c = fmaxf(c, s_sig[16 + u]); }
                s_sig[32] = a; s_sig[33] = c;
            }
            __syncthreads();
            mn = s_sig[32]; mx = s_sig[33];
            __syncthreads();   // everyone read mn/mx before Phase A overwrites slots 32/33
        }
        float denom = mx - mn;
        if (denom <= 0.f) denom = 1.f;

        // Phase A (fused quantize): key = (L<<14)|i, horizontal runs -> run min-KEY.
        unsigned am = 0;
#pragma unroll
        for (int k = 0; k < 16; ++k) {
            int i = (w << 10) + (k << 6) + (int)lane;
            int L;
            if (ismask) {
                L = (int)rintf(src[i] * 10.0f);
            } else {
                // wave0/k0 slots were reduce scratch -> recompute from global (L2-hot)
                float s = (k == 0 && w == 0) ? (1.0f / (1.0f + expf(-src[i]))) : s_sig[i];
                L = (int)rintf((s - mn) / denom * 10.0f);
            }
            bool act = L <= l;
            if (act) am |= 1u << k;
            unsigned key = ((unsigned)L << 14) | (unsigned)i;
            unsigned long long m = __ballot(act);
            unsigned kv = act ? key : BIGK;
            unsigned long long lowmask = (1ull << lane) - 1ull;
            unsigned long long zb = (~m) & lowmask;
            int runstart = zb ? (64 - __clzll(zb)) : 0;
            unsigned v = kv;
#pragma unroll
            for (int d = 1; d < 64; d <<= 1) {
                unsigned o = __shfl_up(v, d, 64);
                if ((int)lane - d >= runstart) v = min(v, o);
            }
            unsigned long long za = (lane == 63u) ? 0ull : ((~m) >> (lane + 1));
            int runend = za ? ((int)lane + __ffsll((long long)za) - 1) : 63;
            unsigned rmin = __shfl(v, runend, 64);
            s_par[i] = act ? rmin : key;
        }

        unsigned amL  = (unsigned)__shfl_up((int)am, 1, 64);
        unsigned am63 = (unsigned)__shfl((int)am, 63, 64);

        // Phase B1: intra-strip unions (own-wave LDS only, no barrier needed)
#pragma unroll
        for (int k = 0; k < 16; ++k) {
            if (!((am >> k) & 1u)) continue;
            int i = (w << 10) + (k << 6) + (int)lane;
            if ((k & 1) && lane == 0u && ((am63 >> (k - 1)) & 1u))
                unionk(par, s_par, (unsigned)i, (unsigned)(i - 1));
            if (k >= 2 && ((am >> (k - 2)) & 1u)) {
                bool leftpair = (lane > 0u) && ((amL >> k) & 1u) && ((amL >> (k - 2)) & 1u);
                if (!leftpair)
                    unionk(par, s_par, (unsigned)i, (unsigned)(i - IMW));
            }
        }
        __syncthreads();

        // Phase B2: inter-strip boundary rows
        if (w >= 1) {
#pragma unroll
            for (int k = 0; k < 2; ++k) {
                if (!((am >> k) & 1u)) continue;
                int i = (w << 10) + (k << 6) + (int)lane;
                if ((int)(s_par[i - IMW] >> 14) <= l) {
                    int col = (k << 6) + (int)lane;
                    bool lact = (lane > 0u) ? (((amL >> k) & 1u) != 0u)
                                            : (k == 1 ? (((am63 >> 0) & 1u) != 0u) : false);
                    bool leftpair = (col != 0) && lact && ((int)(s_par[i - 1 - IMW] >> 14) <= l);
                    if (!leftpair)
                        unionk(par, s_par, (unsigned)i, (unsigned)(i - IMW));
                }
            }
        }
        __syncthreads();

        // emit: sparse atomicMax for roots only (root iff active && par key idx == i)
#pragma unroll
        for (int k = 0; k < 16; ++k) {
            if (!((am >> k) & 1u)) continue;
            int i = (w << 10) + (k << 6) + (int)lane;
            if ((s_par[i] & IMASK) == (unsigned)i) atomicMax(&lr_i[i], l);
        }
        __syncthreads();   // implicit vmcnt(0): all atomics complete before release
        if (tid == 0) flag_release(&flags[blk]);
        return;
    }

    if (blk < 96) {
        // ================= death(img) =================
        int img = blk - 88;
        bool ismask = img < 4;
        const float* src = ismask ? (labels + (size_t)img * NPIX)
                                  : (model_output + (size_t)(img - 4) * NPIX);
        const int* lr_i = lastroot + (size_t)img * NPIX;
        float* s_sig = (float*)smem;   // 64 KB staging (pred), dead after pack build

        // selection overlay (valid only after the post-pack barrier)
        unsigned long long* s_bm = (unsigned long long*)smem;     // 2048
        unsigned* s_keys = (unsigned*)(smem + 2048);              // 1024
        unsigned* s_pay  = (unsigned*)(smem + 3072);              // 1024
        unsigned* s_pc   = (unsigned*)(smem + 4096);              // 1024
        unsigned* s_hist = (unsigned*)(smem + 5120);              // 256
        uint8_t*  s_rtab = (uint8_t*)(smem + 5376);               // 128
        unsigned* s_ctl  = (unsigned*)(smem + 5504);              // 64
        unsigned* s_red  = (unsigned*)(smem + 5568);              // 68

        // ---- quantize pass 1 (pred): sigmoid -> s_sig + minmax ----
        float mn = 0.f, mx = 1.f;
        if (!ismask) {
            float lmn = 1e30f, lmx = -1e30f;
#pragma unroll
            for (int k = 0; k < 16; ++k) {
                int i = (w << 10) + (k << 6) + (int)lane;
                float s = 1.0f / (1.0f + expf(-src[i]));
                s_sig[i] = s;
                lmn = fminf(lmn, s); lmx = fmaxf(lmx, s);
            }
            for (int off = 32; off > 0; off >>= 1) {
                lmn = fminf(lmn, __shfl_down(lmn, off));
                lmx = fmaxf(lmx, __shfl_down(lmx, off));
            }
            if (lane == 0u) { s_sig[w] = lmn; s_sig[16 + w] = lmx; }   // wave0/k0 scratch
            __syncthreads();
            if (tid == 0) {
                float a = s_sig[0], c = s_sig[16];
                for (int u = 1; u < 16; ++u) { a = fminf(a, s_sig[u]); c = fmaxf(c, s_sig[16 + u]); }
                s_sig[32] = a; s_sig[33] = c;
            }
            __syncthreads();
            mn = s_sig[32]; mx = s_sig[33];
            __syncthreads();
        }
        float denom = mx - mn;
        if (denom <= 0.f) denom = 1.f;

        // ---- quantize pass 2: levels into nibble packs (no arrays, no LDS byte map) ----
        unsigned pack0 = 0, pack1 = 0, lmaxk = 0;
#pragma unroll
        for (int k = 0; k < 16; ++k) {
            int i = (w << 10) + (k << 6) + (int)lane;
            int L;
            if (ismask) {
                L = (int)rintf(src[i] * 10.0f);
            } else {
                float s = (k == 0 && w == 0) ? (1.0f / (1.0f + expf(-src[i]))) : s_sig[i];
                L = (int)rintf((s - mn) / denom * 10.0f);
            }
            if (k < 8) pack0 |= (unsigned)L << (k * 4);
            else       pack1 |= (unsigned)L << ((k - 8) * 4);
            lmaxk = max(lmaxk, (unsigned)L);
        }
        for (int off = 32; off > 0; off >>= 1)
            lmaxk = max(lmaxk, (unsigned)__shfl_down((int)lmaxk, off));
        __syncthreads();   // s_sig fully consumed -> overlay becomes valid

        if (lane == 0u) s_red[w] = lmaxk;
        if (tid < 64) s_hist[tid] = 0;
        if (tid < 256) { s_bm[tid] = 0ull; s_keys[tid] = 0xFFFFFFFFu; }
        if (tid < NLVL * NLVL) {
            int d = tid / NLVL, bb0 = tid % NLVL;
            if (d > bb0) {
                float pers = (float)d / 10.0f - (float)bb0 / 10.0f;
                unsigned rk = 0;
                for (int dd = 1; dd <= 10; ++dd)
                    for (int bb = 0; bb < dd; ++bb) {
                        float pp = (float)dd / 10.0f - (float)bb / 10.0f;
                        rk += (pp > pers) ? 1u : 0u;
                    }
                s_rtab[d * NLVL + bb0] = (uint8_t)rk;
            }
        }
        __syncthreads();
        if (tid == 0) { unsigned m = s_red[0]; for (int u = 1; u < 16; ++u) m = max(m, s_red[u]); s_red[16] = m; }

        if (tid < NLVL) flag_acquire(&flags[img * NLVL + tid]);
        __syncthreads();
        int maxL = (int)s_red[16];

        // pass 1: histogram. candidate iff lastroot[i] >= birth (root at birth);
        // death = lastroot+1 clamped to maxL (covers essential class uniformly).
#pragma unroll
        for (int k = 0; k < 16; ++k) {
            int i = (w << 10) + (k << 6) + (int)lane;
            int b = (int)nib4(pack0, pack1, k);
            int lr = lr_i[i];                      // poison 0xAAAAAAAA < 0 == never-root
            if (lr < b) continue;
            int d = min(lr + 1, maxL);
            if (d > b) atomicAdd(&s_hist[s_rtab[d * NLVL + b]], 1u);
        }
        __syncthreads();

        if (tid == 0) {
            unsigned cum = 0, rstar = 63, cless = 0;
            for (int r = 0; r < 56; ++r) {
                if (cum + s_hist[r] >= 256u && rstar == 63u) { rstar = r; cless = cum; }
                cum += s_hist[r];
            }
            if (rstar == 63u) cless = cum;
            s_ctl[0] = rstar; s_ctl[1] = cless;
            s_ctl[2] = (rstar == 63u) ? 0u : (256u - cless);
            s_ctl[3] = 0;
        }
        __syncthreads();
        unsigned rstar = s_ctl[0], cless = s_ctl[1], mneed = s_ctl[2];

        // pass 2: compact rank<r* (key + (b,d) payload); bitmap for rank==r*
#pragma unroll
        for (int k = 0; k < 16; ++k) {
            int i = (w << 10) + (k << 6) + (int)lane;
            int b = (int)nib4(pack0, pack1, k);
            int lr = lr_i[i];
            if (lr < b) continue;
            int d = min(lr + 1, maxL);
            if (d <= b) continue;
            unsigned r = s_rtab[d * NLVL + b];
            if (r < rstar) {
                unsigned pos = atomicAdd(&s_ctl[3], 1u);
                if (pos < 256u) {
                    s_keys[pos] = (r << 14) | (unsigned)i;
                    s_pay[pos]  = ((unsigned)b << 8) | (unsigned)d;
                }
            } else if (r == rstar) {
                atomicOr(&s_bm[i >> 6], 1ull << (i & 63));
            }
        }
        __syncthreads();

        // rank-sort 256 keys ascending, payload moves with key (2 barriers)
        unsigned myk = 0, myp = 0, mypos = 0;
        if (tid < 256) {
            myk = s_keys[tid];
            myp = s_pay[tid];
            unsigned cnt = 0;
            for (int j = 0; j < 256; ++j) {
                unsigned y = s_keys[j];
                cnt += (y < myk) || (y == myk && j < tid);
            }
            mypos = cnt;
        }
        __syncthreads();
        if (tid < 256) { s_keys[mypos] = myk; s_pay[mypos] = myp; }

        // bucket r*: popcount prefix via wave shfl scan (2 barriers)
        if (tid < 256) {
            unsigned v = (unsigned)__popcll(s_bm[tid]);
#pragma unroll
            for (int d = 1; d < 64; d <<= 1) {
                unsigned o = __shfl_up(v, d, 64);
                if ((int)lane >= d) v += o;
            }
            s_pc[tid] = v;
            if (lane == 63u) s_ctl[8 + (tid >> 6)] = v;
        }
        __syncthreads();
        if (tid < 256) {
            unsigned add = 0; int wq = tid >> 6;
            for (int u = 0; u < wq; ++u) add += s_ctl[8 + u];
            s_pc[tid] += add;
        }
        __syncthreads();
        if (rstar != 63u) {
#pragma unroll
            for (int k = 0; k < 16; ++k) {
                int i = (w << 10) + (k << 6) + (int)lane;
                if (!((s_bm[i >> 6] >> (i & 63)) & 1ull)) continue;
                unsigned wq = i >> 6;
                unsigned order = (wq ? s_pc[wq - 1] : 0u)
                               + (unsigned)__popcll(s_bm[wq] & ((1ull << (i & 63)) - 1ull));
                if (order < mneed) {
                    int b = (int)nib4(pack0, pack1, k);
                    int d = min(lr_i[i] + 1, maxL);
                    s_keys[cless + order] = (rstar << 14) | (unsigned)i;
                    s_pay[cless + order]  = ((unsigned)b << 8) | (unsigned)d;
                }
            }
        }
        __syncthreads();

        if (tid < 256) {
            unsigned key = s_keys[tid];
            float p = 0.f, bv = 0.f, dv = 0.f;
            if (key != 0xFFFFFFFFu) {
                unsigned pay = s_pay[tid];
                bv = (float)(pay >> 8)   / 10.0f;
                dv = (float)(pay & 255u) / 10.0f;
                p = dv - bv;
            }
            outP[img * 256 + tid] = p;
            outB[img * 256 + tid] = bv;
            outD[img * 256 + tid] = dv;
        }
        __syncthreads();
        if (tid == 0) flag_release(&dflags[img]);
        return;
    }

    // ================= wdist (verified body) =================
    {
        if (tid < 8) flag_acquire(&dflags[tid]);
        __syncthreads();

        float* part = (float*)smem;          // [16]
        float* dist = (float*)(smem + 64);   // [4]
        int s = tid >> 8;
        int slot = tid & 255;
        int mi = s * 256 + slot;
        int pi = (4 + s) * 256 + slot;
        float p1 = outP[mi], b1 = outB[mi], d1 = outD[mi];
        float p2 = outP[pi], b2 = outB[pi], d2 = outD[pi];
        bool h1 = p1 > 0.f, h2 = p2 > 0.f;
        float cost = 0.f;
        if (h1 && h2)      cost = (b1 - b2) * (b1 - b2) + (d1 - d2) * (d1 - d2);
        else if (h1)       cost = p1 * p1 * 0.5f;
        else if (h2)       cost = p2 * p2 * 0.5f;

        for (int off = 32; off > 0; off >>= 1) cost += __shfl_down(cost, off);
        int wv = tid >> 6;
        if (lane == 0u) part[wv] = cost;
        __syncthreads();
        if (tid < 4) {
            float sum = part[tid * 4] + part[tid * 4 + 1] + part[tid * 4 + 2] + part[tid * 4 + 3];
            dist[tid] = sqrtf(sum + 1e-12f);
        }
        __syncthreads();
        if (tid == 0)
            out[0] = 0.01f * (dist[0] + dist[1] + dist[2] + dist[3]) / 4.0f;
    }
}

// ws layout (bytes):
//   lastroot i32[8][16384]      @ 0        (524288)  -- poison 0xAAAAAAAA == -inf (signed)
//   outP/outB/outD f32[8][256]  @ 524288   (24576)
//   flags u32[88]               @ 548864   (352)
//   dflags u32[8]               @ 549216   (32)
extern "C" void kernel_launch(void* const* d_in, const int* in_sizes, int n_in,
                              void* d_out, int out_size, void* d_ws, size_t ws_size,
                              hipStream_t stream)
{
    const float* model_output = (const float*)d_in[0];
    const float* labels = (const float*)d_in[1];
    char* ws = (char*)d_ws;
    int* lastroot = (int*)ws;
    float* outP = (float*)(ws + 524288);
    float* outB = outP + NIMG * 256;
    float* outD = outB + NIMG * 256;
    unsigned* flags = (unsigned*)(ws + 548864);
    unsigned* dflags = (unsigned*)(ws + 549216);
    float* out = (float*)d_out;

    topo_fused<<<97, 1024, 0, stream>>>(model_output, labels, lastroot,
                                        outP, outB, outD, flags, dflags, out);
}